// Round 2
// baseline (2970.701 us; speedup 1.0000x reference)
//
#include <hip/hip_runtime.h>
#include <math.h>

// Problem constants
#define Bc 8
#define Nc 19
#define Tc 1000
#define Dc 512
#define BTc (Bc*Tc)        // 8000
#define Mc (BTc*Nc)        // 152000 rows
#define BM 128             // rows per gemm block
#define GRID_M ((Mc + BM - 1)/BM)   // 1188 (last block 64 valid rows)

typedef short bf16x8 __attribute__((ext_vector_type(8)));
typedef float f32x4 __attribute__((ext_vector_type(4)));

__device__ __forceinline__ unsigned short f2bf(float x) {
    unsigned int u = __float_as_uint(x);
    return (unsigned short)((u + 0x7FFFu + ((u >> 16) & 1u)) >> 16);  // RNE
}

// async global->LDS, 16B per lane. LDS dest is WAVE-UNIFORM base + lane*16.
__device__ __forceinline__ void gload_lds16(const void* gsrc, void* ldst) {
    __builtin_amdgcn_global_load_lds(
        (const __attribute__((address_space(1))) void*)gsrc,
        (__attribute__((address_space(3))) void*)ldst,
        16, 0, 0);
}

// ---------------------------------------------------------------------------
// Shuffle W (2,512,512) fp32 -> bf16 in MFMA B-operand layout:
// Wshuf[((layer*16+ks)*32 + ntile)*512 + lane*8 + j] = W[layer][ks*32+(lane>>4)*8+j][ntile*16+(lane&15)]
// so each lane's B-fragment is one contiguous 16B load, and each K-step's
// 32 fragments are one contiguous 32KB block (ideal for global_load_lds).
// ---------------------------------------------------------------------------
__global__ __launch_bounds__(256) void prep_w_kernel(const float* __restrict__ W,
                                                     unsigned short* __restrict__ Wshuf) {
    int tid = blockIdx.x * 256 + threadIdx.x;   // 2*16*32*512 = 524288 total
    int j     = tid & 7;
    int lane  = (tid >> 3) & 63;
    int ntile = (tid >> 9) & 31;
    int ks    = (tid >> 14) & 15;
    int layer = (tid >> 18) & 1;
    int k = ks * 32 + ((lane >> 4) << 3) + j;
    int n = ntile * 16 + (lane & 15);
    Wshuf[tid] = f2bf(W[layer * (Dc*Dc) + k * Dc + n]);
}

// ---------------------------------------------------------------------------
// Mix kernel: one block per (b,t). Row-normalized softplus adjacency,
// P = 0.95*I + 0.05*adj_norm, then x_mixed = P @ x, written bf16 to Amix.
// Each thread owns cols d0,d0+1 across all 19 rows -> x goes straight to
// registers (no LDS round-trip); loads issued before the P barriers so the
// HBM latency hides under softplus + reduction.
// ---------------------------------------------------------------------------
__global__ __launch_bounds__(256) void mix_kernel(const float* xin,
                                                  const float* __restrict__ adj,
                                                  const float* __restrict__ edge_w,
                                                  const float* __restrict__ edge_b,
                                                  unsigned short* __restrict__ Amix) {
    __shared__ float P[Nc*Nc];
    __shared__ float rs[Nc];
    int bt = blockIdx.x;
    int b  = bt / Tc;
    int t  = bt - b * Tc;
    int tid = threadIdx.x;
    int d0 = tid * 2;

    // issue the x loads FIRST (independent of P) so they fly during softplus
    float2 xv[Nc];
    const float* xbase = xin + ((size_t)b * Nc * Tc + t) * Dc + d0;
    #pragma unroll
    for (int j = 0; j < Nc; ++j)
        xv[j] = *(const float2*)(xbase + (size_t)j * Tc * Dc);

    float ew = edge_w[0], eb = edge_b[0];
    for (int idx = tid; idx < Nc*Nc; idx += 256) {
        float z = fmaf(adj[(size_t)bt * (Nc*Nc) + idx], ew, eb);
        P[idx] = fmaxf(z, 0.f) + log1pf(expf(-fabsf(z)));   // stable softplus
    }
    __syncthreads();
    if (tid < Nc) {
        float s = 0.f;
        #pragma unroll
        for (int j = 0; j < Nc; ++j) s += P[tid*Nc + j];
        rs[tid] = 0.05f / (s + 1e-6f);
    }
    __syncthreads();
    for (int idx = tid; idx < Nc*Nc; idx += 256) {
        int i = idx / Nc;
        int j = idx - i*Nc;
        float v = P[idx] * rs[i];
        if (i == j) v += 0.95f;
        P[idx] = v;
    }
    __syncthreads();

    size_t obase = (size_t)bt * Nc * Dc + d0;
    #pragma unroll
    for (int i = 0; i < Nc; ++i) {
        float a0 = 0.f, a1 = 0.f;
        #pragma unroll
        for (int j = 0; j < Nc; ++j) {
            float p = P[i*Nc + j];
            a0 = fmaf(p, xv[j].x, a0);
            a1 = fmaf(p, xv[j].y, a1);
        }
        unsigned int pack = (unsigned int)f2bf(a0) | ((unsigned int)f2bf(a1) << 16);
        *(unsigned int*)&Amix[obase + (size_t)i * Dc] = pack;
    }
}

// ---------------------------------------------------------------------------
// Fused GEMM: C(128 x 512) = Amix_tile @ W + bias + residual, then LayerNorm
// + exact-erf GELU, stored fp32 to out (B,N,T,D) layout.
// 512 threads = 8 waves in a 2(row) x 4(col) grid; each wave owns 64x128.
// K-loop: 16 steps of BK=32; A(128x32, 8KB) and W(32x512, fragment-order)
// double-buffered in LDS via global_load_lds dwordx4.
// LDS = exactly 80 KB (epilogue scratch ALIASES the staging buffers) and
// __launch_bounds__(512,4) pins VGPR<=128 -> 2 blocks/CU, so one block's
// waves execute while the other sits in its barrier vmcnt-drain.
// ---------------------------------------------------------------------------
__global__ __launch_bounds__(512, 4) void gemm_fused_kernel(
        const unsigned short* __restrict__ Amix,
        const unsigned short* __restrict__ Wshuf,   // this layer's shuffled W
        const float* xin,                           // residual source (may alias out)
        const float* __restrict__ bias,
        const float* __restrict__ gamma,
        const float* __restrict__ beta,
        float* out) {
    // 81920 B total: [A dbuf 2x8KB][W dbuf 2x32KB]; epilogue scratch aliases front
    __shared__ __align__(16) unsigned char smem[81920];
    unsigned short* Alds0 = (unsigned short*)smem;             // 2 x 4096 ushorts
    unsigned short* Wlds0 = (unsigned short*)(smem + 16384);   // 2 x 16384 ushorts

    const int tid  = threadIdx.x;
    const int wid  = tid >> 6;        // 0..7
    const int lane = tid & 63;
    const int wr   = wid >> 2;        // 0..1 : row half
    const int wc   = wid & 3;         // 0..3 : col quarter
    const int quad = lane >> 4;
    const int ln   = lane & 15;
    const int r0   = blockIdx.x * BM;

    // --- staging geometry ---
    // A: one gload per wave per step. lane l -> row wid*16 + (l>>2), 16B chunk (l&3).
    int arow = wid*16 + (lane>>2);
    int agr  = r0 + arow; if (agr > Mc-1) agr = Mc-1;            // tail clamp
    const unsigned short* asrc = Amix + (size_t)agr*Dc + (lane&3)*8;

    // W: 4 gloads per wave per step; step s block = Wshuf + s*16384 ushorts.
    const unsigned short* wsrc = Wshuf + (size_t)wid*512 + (size_t)lane*8;

    f32x4 acc[4][8];
    #pragma unroll
    for (int rf = 0; rf < 4; ++rf)
        #pragma unroll
        for (int cf = 0; cf < 8; ++cf)
            acc[rf][cf] = (f32x4){0.f, 0.f, 0.f, 0.f};

    // prologue: stage step 0 into buffer 0
    gload_lds16(asrc, Alds0 + wid*512);
    #pragma unroll
    for (int i = 0; i < 4; ++i)
        gload_lds16(wsrc + i*4096, Wlds0 + wid*512 + i*4096);
    __syncthreads();

    #pragma unroll 2
    for (int s = 0; s < 16; ++s) {
        const int cb = s & 1;
        if (s < 15) {
            const int nb = cb ^ 1;
            gload_lds16(asrc + (s+1)*32, Alds0 + nb*4096 + wid*512);
            const unsigned short* ws = wsrc + (size_t)(s+1)*16384;
            #pragma unroll
            for (int i = 0; i < 4; ++i)
                gload_lds16(ws + i*4096, Wlds0 + nb*16384 + wid*512 + i*4096);
        }
        bf16x8 a[4], b[8];
        #pragma unroll
        for (int rf = 0; rf < 4; ++rf)
            a[rf] = *(const bf16x8*)&Alds0[cb*4096 + (wr*64 + rf*16 + ln)*32 + quad*8];
        #pragma unroll
        for (int cf = 0; cf < 8; ++cf)
            b[cf] = *(const bf16x8*)&Wlds0[cb*16384 + ((wc*8 + cf)*64 + lane)*8];
        #pragma unroll
        for (int rf = 0; rf < 4; ++rf)
            #pragma unroll
            for (int cf = 0; cf < 8; ++cf)
                acc[rf][cf] = __builtin_amdgcn_mfma_f32_16x16x32_bf16(a[rf], b[cf], acc[rf][cf], 0, 0, 0);
        __syncthreads();   // drains next-step stage loads + protects buffers
    }
    // staging buffers dead from here; alias epilogue scratch onto smem
    float* ps1  = (float*)smem;          // [BM][4] = 2 KB
    float* ps2  = ps1 + BM*4;            // [BM][4] = 2 KB
    float* mu_s = ps2 + BM*4;            // [BM]
    float* rs_s = mu_s + BM;             // [BM]

    // --- epilogue: bias + residual + LN + exact GELU ---
    float bcol[8], gcol[8], betc[8];
    #pragma unroll
    for (int cf = 0; cf < 8; ++cf) {
        int col = wc*128 + cf*16 + ln;
        bcol[cf] = bias[col];
        gcol[cf] = gamma[col];
        betc[cf] = beta[col];
    }

    unsigned int roff[4][4];
    float s1[4][4], s2[4][4];
    #pragma unroll
    for (int rf = 0; rf < 4; ++rf) {
        #pragma unroll
        for (int reg = 0; reg < 4; ++reg) {
            int gr = r0 + wr*64 + rf*16 + quad*4 + reg;
            int g  = gr < Mc ? gr : Mc-1;        // clamp (dead rows read row Mc-1)
            int bt = g / Nc;
            int n  = g - bt*Nc;
            int b  = bt / Tc;
            int t  = bt - b*Tc;
            roff[rf][reg] = (unsigned int)(((b*Nc + n)*Tc + t)*Dc);
            float S1 = 0.f, S2 = 0.f;
            #pragma unroll
            for (int cf = 0; cf < 8; ++cf) {
                int col = wc*128 + cf*16 + ln;
                float z = acc[rf][cf][reg] + bcol[cf] + xin[roff[rf][reg] + col];
                acc[rf][cf][reg] = z;
                S1 += z;
                S2 = fmaf(z, z, S2);
            }
            s1[rf][reg] = S1;
            s2[rf][reg] = S2;
        }
    }

    // reduce across the 16 lanes of each quad (rows are quad-local)
    #pragma unroll
    for (int rf = 0; rf < 4; ++rf) {
        #pragma unroll
        for (int reg = 0; reg < 4; ++reg) {
            float a = s1[rf][reg], c = s2[rf][reg];
            #pragma unroll
            for (int off = 1; off < 16; off <<= 1) {
                a += __shfl_xor(a, off, 64);
                c += __shfl_xor(c, off, 64);
            }
            if (ln == 0) {
                int R = wr*64 + rf*16 + quad*4 + reg;
                ps1[R*4 + wc] = a;
                ps2[R*4 + wc] = c;
            }
        }
    }
    __syncthreads();
    if (tid < BM) {
        float a = ps1[tid*4+0] + ps1[tid*4+1] + ps1[tid*4+2] + ps1[tid*4+3];
        float c = ps2[tid*4+0] + ps2[tid*4+1] + ps2[tid*4+2] + ps2[tid*4+3];
        float mu = a * (1.0f/Dc);
        float var = c * (1.0f/Dc) - mu*mu;
        mu_s[tid] = mu;
        rs_s[tid] = rsqrtf(var + 1e-5f);
    }
    __syncthreads();

    // LN + exact GELU + store (guard tail rows)
    #pragma unroll
    for (int rf = 0; rf < 4; ++rf) {
        #pragma unroll
        for (int reg = 0; reg < 4; ++reg) {
            int R  = wr*64 + rf*16 + quad*4 + reg;
            int gr = r0 + R;
            if (gr < Mc) {
                float mu   = mu_s[R];
                float rstd = rs_s[R];
                unsigned int ro = roff[rf][reg];
                #pragma unroll
                for (int cf = 0; cf < 8; ++cf) {
                    int col = wc*128 + cf*16 + ln;
                    float v = (acc[rf][cf][reg] - mu) * rstd * gcol[cf] + betc[cf];
                    float g = 0.5f * v * (1.0f + erff(v * 0.70710678118654752f));
                    out[ro + col] = g;
                }
            }
        }
    }
}

// ---------------------------------------------------------------------------
extern "C" void kernel_launch(void* const* d_in, const int* in_sizes, int n_in,
                              void* d_out, int out_size, void* d_ws, size_t ws_size,
                              hipStream_t stream) {
    const float* features  = (const float*)d_in[0];
    const float* adjacency = (const float*)d_in[1];
    const float* edge_w    = (const float*)d_in[2];
    const float* edge_b    = (const float*)d_in[3];
    const float* W         = (const float*)d_in[4];
    const float* bias      = (const float*)d_in[5];
    const float* gamma     = (const float*)d_in[6];
    const float* beta      = (const float*)d_in[7];
    float* out = (float*)d_out;

    // ws layout: [Wshuf: 2*512*512 bf16 = 1 MB][Amix: 152000*512 bf16 = 155.6 MB]
    unsigned short* Wshuf = (unsigned short*)d_ws;
    unsigned short* Amix  = Wshuf + 2*Dc*Dc;

    prep_w_kernel<<<2048, 256, 0, stream>>>(W, Wshuf);

    // layer 0: input = features
    mix_kernel<<<BTc, 256, 0, stream>>>(features, adjacency, edge_w, edge_b, Amix);
    gemm_fused_kernel<<<GRID_M, 512, 0, stream>>>(Amix, Wshuf, features,
                                                  bias, gamma, beta, out);
    // layer 1: input = out (d_out holds x in (B,N,T,D) layout)
    mix_kernel<<<BTc, 256, 0, stream>>>(out, adjacency, edge_w, edge_b, Amix);
    gemm_fused_kernel<<<GRID_M, 512, 0, stream>>>(Amix, Wshuf + Dc*Dc, out,
                                                  bias + Dc, gamma + Dc, beta + Dc, out);
}

// Round 3
// 1313.924 us; speedup vs baseline: 2.2609x; 2.2609x over previous
//
#include <hip/hip_runtime.h>
#include <math.h>

// Problem constants
#define Bc 8
#define Nc 19
#define Tc 1000
#define Dc 512
#define BTc (Bc*Tc)        // 8000
#define Mc (BTc*Nc)        // 152000 rows
#define BMg 64             // rows per gemm block; 152000/64 = 2375 exactly (no tail)
#define GRID_M (Mc/BMg)    // 2375

typedef short bf16x8 __attribute__((ext_vector_type(8)));
typedef float f32x4 __attribute__((ext_vector_type(4)));

__device__ __forceinline__ unsigned short f2bf(float x) {
    unsigned int u = __float_as_uint(x);
    return (unsigned short)((u + 0x7FFFu + ((u >> 16) & 1u)) >> 16);  // RNE
}

// async global->LDS, 16B per lane. LDS dest is WAVE-UNIFORM base + lane*16.
__device__ __forceinline__ void gload_lds16(const void* gsrc, void* ldst) {
    __builtin_amdgcn_global_load_lds(
        (const __attribute__((address_space(1))) void*)gsrc,
        (__attribute__((address_space(3))) void*)ldst,
        16, 0, 0);
}

// ---------------------------------------------------------------------------
// Shuffle W (2,512,512) fp32 -> bf16 in MFMA B-operand layout:
// Wshuf[((layer*16+ks)*32 + ntile)*512 + lane*8 + j] = W[layer][ks*32+(lane>>4)*8+j][ntile*16+(lane&15)]
// Each K-step's 32 fragments are one contiguous 32KB block.
// ---------------------------------------------------------------------------
__global__ __launch_bounds__(256) void prep_w_kernel(const float* __restrict__ W,
                                                     unsigned short* __restrict__ Wshuf) {
    int tid = blockIdx.x * 256 + threadIdx.x;   // 2*16*32*512 = 524288 total
    int j     = tid & 7;
    int lane  = (tid >> 3) & 63;
    int ntile = (tid >> 9) & 31;
    int ks    = (tid >> 14) & 15;
    int layer = (tid >> 18) & 1;
    int k = ks * 32 + ((lane >> 4) << 3) + j;
    int n = ntile * 16 + (lane & 15);
    Wshuf[tid] = f2bf(W[layer * (Dc*Dc) + k * Dc + n]);
}

// ---------------------------------------------------------------------------
// Mix kernel: one block per (b,t). Row-normalized softplus adjacency folded
// directly into the accumulation: out_i = rs[i]*sum_j(sp_ij*x_j) + 0.95*x_i.
// x rows go straight to registers; loads issued before the P barriers.
// ---------------------------------------------------------------------------
__global__ __launch_bounds__(256) void mix_kernel(const float* xin,
                                                  const float* __restrict__ adj,
                                                  const float* __restrict__ edge_w,
                                                  const float* __restrict__ edge_b,
                                                  unsigned short* __restrict__ Amix) {
    __shared__ float P[Nc*Nc];
    __shared__ float rs[Nc];
    int bt = blockIdx.x;
    int b  = bt / Tc;
    int t  = bt - b * Tc;
    int tid = threadIdx.x;
    int d0 = tid * 2;

    // issue the x loads FIRST (independent of P) so they fly during softplus
    float2 xv[Nc];
    const float* xbase = xin + ((size_t)b * Nc * Tc + t) * Dc + d0;
    #pragma unroll
    for (int j = 0; j < Nc; ++j)
        xv[j] = *(const float2*)(xbase + (size_t)j * Tc * Dc);

    float ew = edge_w[0], eb = edge_b[0];
    for (int idx = tid; idx < Nc*Nc; idx += 256) {
        float z = fmaf(adj[(size_t)bt * (Nc*Nc) + idx], ew, eb);
        P[idx] = fmaxf(z, 0.f) + log1pf(expf(-fabsf(z)));   // stable softplus
    }
    __syncthreads();
    if (tid < Nc) {
        float s = 0.f;
        #pragma unroll
        for (int j = 0; j < Nc; ++j) s += P[tid*Nc + j];
        rs[tid] = 0.05f / (s + 1e-6f);
    }
    __syncthreads();

    size_t obase = (size_t)bt * Nc * Dc + d0;
    #pragma unroll
    for (int i = 0; i < Nc; ++i) {
        float a0 = 0.f, a1 = 0.f;
        #pragma unroll
        for (int j = 0; j < Nc; ++j) {
            float p = P[i*Nc + j];
            a0 = fmaf(p, xv[j].x, a0);
            a1 = fmaf(p, xv[j].y, a1);
        }
        float r = rs[i];
        a0 = fmaf(a0, r, 0.95f * xv[i].x);
        a1 = fmaf(a1, r, 0.95f * xv[i].y);
        unsigned int pack = (unsigned int)f2bf(a0) | ((unsigned int)f2bf(a1) << 16);
        *(unsigned int*)&Amix[obase + (size_t)i * Dc] = pack;
    }
}

// ---------------------------------------------------------------------------
// Fused GEMM: C(64 x 512) = Amix_tile @ W + bias + residual, LN, exact GELU.
// 256 threads = 4 waves; wave w owns cols [w*128, w*128+128) of ALL 64 rows.
// K-loop: 16 steps of BK=32, double-buffered LDS (A 2x4KB, W 2x32KB = 72KB
// -> 2 blocks/CU at <=256 unified regs). Counted s_waitcnt vmcnt(9) + raw
// s_barrier: prefetch stays in flight across barriers (no vmcnt(0) drain).
// Per step per wave: 1 A gload + 8 W gloads = 9 outstanding.
// ---------------------------------------------------------------------------
__global__ __launch_bounds__(256, 2) void gemm_fused_kernel(
        const unsigned short* __restrict__ Amix,
        const unsigned short* __restrict__ Wshuf,   // this layer's shuffled W
        const float* xin,                           // residual source (may alias out)
        const float* __restrict__ bias,
        const float* __restrict__ gamma,
        const float* __restrict__ beta,
        float* out) {
    // 73728 B: [A dbuf 2x4KB @0][W dbuf 2x32KB @8192]; epilogue scratch aliases front
    __shared__ __align__(16) unsigned char smem[73728];
    unsigned short* Alds = (unsigned short*)smem;              // 2 x 2048 ushorts
    unsigned short* Wlds = (unsigned short*)(smem + 8192);     // 2 x 16384 ushorts

    const int tid  = threadIdx.x;
    const int wid  = tid >> 6;        // 0..3 : col quarter
    const int lane = tid & 63;
    const int quad = lane >> 4;
    const int ln   = lane & 15;
    const int r0   = blockIdx.x * BMg;

    // A staging: wave w -> rows w*16+(l>>2), 16B chunk (l&3). 1 gload/wave/step.
    const int arow = wid*16 + (lane>>2);
    const unsigned short* asrc = Amix + (size_t)(r0 + arow)*Dc + (lane&3)*8;
    // W staging: chunk c = wid*8+i (1KB each), 8 gloads/wave/step.
    const unsigned short* wsrc = Wshuf + (size_t)wid*4096 + (size_t)lane*8;

    f32x4 acc[4][8];
    #pragma unroll
    for (int rf = 0; rf < 4; ++rf)
        #pragma unroll
        for (int cf = 0; cf < 8; ++cf)
            acc[rf][cf] = (f32x4){0.f, 0.f, 0.f, 0.f};

#define STAGE(kk, buf) do {                                                   \
        gload_lds16(asrc + (kk)*32, Alds + (buf)*2048 + wid*512);             \
        _Pragma("unroll")                                                     \
        for (int i = 0; i < 8; ++i)                                           \
            gload_lds16(wsrc + (size_t)(kk)*16384 + i*512,                    \
                        Wlds + (buf)*16384 + wid*4096 + i*512);               \
    } while (0)

    STAGE(0, 0);                      // 9 outstanding
    #pragma unroll 2
    for (int s = 0; s < 16; ++s) {
        const int cb = s & 1;
        if (s < 15) {
            STAGE(s+1, cb ^ 1);       // WAR-safe: buf cb^1 reads finished before
                                      // barrier-2 of step s-1 (below)
            // oldest 9 (this step's buffer) must land; newest 9 stay in flight
            asm volatile("s_waitcnt vmcnt(9)" ::: "memory");
        } else {
            asm volatile("s_waitcnt vmcnt(0)" ::: "memory");
        }
        __builtin_amdgcn_s_barrier();          // all waves' cb loads landed
        bf16x8 a[4], b[8];
        #pragma unroll
        for (int rf = 0; rf < 4; ++rf)
            a[rf] = *(const bf16x8*)&Alds[cb*2048 + (rf*16 + ln)*32 + quad*8];
        #pragma unroll
        for (int cf = 0; cf < 8; ++cf)
            b[cf] = *(const bf16x8*)&Wlds[cb*16384 + ((wid*8 + cf)*64 + lane)*8];
        #pragma unroll
        for (int rf = 0; rf < 4; ++rf)
            #pragma unroll
            for (int cf = 0; cf < 8; ++cf)
                acc[rf][cf] = __builtin_amdgcn_mfma_f32_16x16x32_bf16(a[rf], b[cf], acc[rf][cf], 0, 0, 0);
        __builtin_amdgcn_sched_barrier(0);     // pin reads/MFMAs before barrier-2
        __builtin_amdgcn_s_barrier();          // all reads of cb done -> next step may overwrite
    }
#undef STAGE

    // staging buffers dead; alias epilogue scratch (final barrier-2 synced all reads)
    float* ps1  = (float*)smem;          // [64][4] = 1 KB
    float* ps2  = ps1 + BMg*4;           // [64][4] = 1 KB
    float* mu_s = ps2 + BMg*4;           // [64]
    float* rs_s = mu_s + BMg;            // [64]

    // --- epilogue: bias + residual + LN + exact GELU ---
    float bcol[8], gcol[8], betc[8];
    #pragma unroll
    for (int cf = 0; cf < 8; ++cf) {
        int col = wid*128 + cf*16 + ln;
        bcol[cf] = bias[col];
        gcol[cf] = gamma[col];
        betc[cf] = beta[col];
    }

    unsigned int roff[4][4];
    float s1[4][4], s2[4][4];
    #pragma unroll
    for (int rf = 0; rf < 4; ++rf) {
        #pragma unroll
        for (int reg = 0; reg < 4; ++reg) {
            int gr = r0 + rf*16 + quad*4 + reg;
            int bt = gr / Nc;
            int n  = gr - bt*Nc;
            int b  = bt / Tc;
            int t  = bt - b*Tc;
            roff[rf][reg] = (unsigned int)(((b*Nc + n)*Tc + t)*Dc);
            float S1 = 0.f, S2 = 0.f;
            #pragma unroll
            for (int cf = 0; cf < 8; ++cf) {
                int col = wid*128 + cf*16 + ln;
                float z = acc[rf][cf][reg] + bcol[cf] + xin[roff[rf][reg] + col];
                acc[rf][cf][reg] = z;
                S1 += z;
                S2 = fmaf(z, z, S2);
            }
            s1[rf][reg] = S1;
            s2[rf][reg] = S2;
        }
    }

    // reduce across the 16 lanes of each quad (rows are quad-local)
    #pragma unroll
    for (int rf = 0; rf < 4; ++rf) {
        #pragma unroll
        for (int reg = 0; reg < 4; ++reg) {
            float a = s1[rf][reg], c = s2[rf][reg];
            #pragma unroll
            for (int off = 1; off < 16; off <<= 1) {
                a += __shfl_xor(a, off, 64);
                c += __shfl_xor(c, off, 64);
            }
            if (ln == 0) {
                int R = rf*16 + quad*4 + reg;
                ps1[R*4 + wid] = a;
                ps2[R*4 + wid] = c;
            }
        }
    }
    __syncthreads();
    if (tid < BMg) {
        float a = ps1[tid*4+0] + ps1[tid*4+1] + ps1[tid*4+2] + ps1[tid*4+3];
        float c = ps2[tid*4+0] + ps2[tid*4+1] + ps2[tid*4+2] + ps2[tid*4+3];
        float mu = a * (1.0f/Dc);
        float var = c * (1.0f/Dc) - mu*mu;
        mu_s[tid] = mu;
        rs_s[tid] = rsqrtf(var + 1e-5f);
    }
    __syncthreads();

    // LN + exact GELU + store
    #pragma unroll
    for (int rf = 0; rf < 4; ++rf) {
        #pragma unroll
        for (int reg = 0; reg < 4; ++reg) {
            int R = rf*16 + quad*4 + reg;
            float mu   = mu_s[R];
            float rstd = rs_s[R];
            unsigned int ro = roff[rf][reg];
            #pragma unroll
            for (int cf = 0; cf < 8; ++cf) {
                int col = wid*128 + cf*16 + ln;
                float v = (acc[rf][cf][reg] - mu) * rstd * gcol[cf] + betc[cf];
                float g = 0.5f * v * (1.0f + erff(v * 0.70710678118654752f));
                out[ro + col] = g;
            }
        }
    }
}

// ---------------------------------------------------------------------------
extern "C" void kernel_launch(void* const* d_in, const int* in_sizes, int n_in,
                              void* d_out, int out_size, void* d_ws, size_t ws_size,
                              hipStream_t stream) {
    const float* features  = (const float*)d_in[0];
    const float* adjacency = (const float*)d_in[1];
    const float* edge_w    = (const float*)d_in[2];
    const float* edge_b    = (const float*)d_in[3];
    const float* W         = (const float*)d_in[4];
    const float* bias      = (const float*)d_in[5];
    const float* gamma     = (const float*)d_in[6];
    const float* beta      = (const float*)d_in[7];
    float* out = (float*)d_out;

    // ws layout: [Wshuf: 2*512*512 bf16 = 1 MB][Amix: 152000*512 bf16 = 155.6 MB]
    unsigned short* Wshuf = (unsigned short*)d_ws;
    unsigned short* Amix  = Wshuf + 2*Dc*Dc;

    prep_w_kernel<<<2048, 256, 0, stream>>>(W, Wshuf);

    // layer 0: input = features
    mix_kernel<<<BTc, 256, 0, stream>>>(features, adjacency, edge_w, edge_b, Amix);
    gemm_fused_kernel<<<GRID_M, 256, 0, stream>>>(Amix, Wshuf, features,
                                                  bias, gamma, beta, out);
    // layer 1: input = out (d_out holds x in (B,N,T,D) layout)
    mix_kernel<<<BTc, 256, 0, stream>>>(out, adjacency, edge_w, edge_b, Amix);
    gemm_fused_kernel<<<GRID_M, 256, 0, stream>>>(Amix, Wshuf + Dc*Dc, out,
                                                  bias + Dc, gamma + Dc, beta + Dc, out);
}